// Round 9
// baseline (1097.058 us; speedup 1.0000x reference)
//
#include <hip/hip_runtime.h>
#include <hip/hip_bf16.h>

#define B_ 32
#define C_ 48
#define H_ 64
#define W_ 128
#define K_ 5
#define SLAB (C_*H_*W_)
#define RS 56                 // carry row stride in bf16 shorts (112 B)
#define RB 112                // row stride bytes
#define ROWS 136
#define CBUF (ROWS*RS)        // shorts per buffer
#define CBYTES (ROWS*RB)      // 15232 B per buffer
#define WC (W_*C_)
#define HC (H_*C_)
#define KBN 8                 // dense K' = 256: k' = k*48 + i

typedef __attribute__((ext_vector_type(8))) short short8;
typedef __attribute__((ext_vector_type(4))) float f32x4;
typedef unsigned short ushort;

__device__ __forceinline__ void lbar() {
  asm volatile("s_waitcnt lgkmcnt(0)\n\ts_barrier" ::: "memory");
}

__device__ __forceinline__ unsigned short f2bf(float f) {
  union { float f; unsigned u; } v; v.f = f;
  unsigned r = v.u + 0x7fffu + ((v.u >> 16) & 1u);
  return (unsigned short)(r >> 16);
}

__device__ __forceinline__ unsigned pk2(float a, float b) {
  union { __hip_bfloat162 h; unsigned u; } z;
  z.h = __float22bfloat162_rn(float2{a, b});
  return z.u;
}

// Weights as MFMA A operand, dense K' (k' = k*48 + i; pad 240..255 -> 0).
__device__ __forceinline__ void load_wA(const float* __restrict__ wgt,
                                        const float* __restrict__ bias,
                                        short8 Aw[3][KBN], f32x4 bv[3],
                                        int l15, int q8, int c0) {
#pragma unroll
  for (int mt = 0; mt < 3; ++mt) {
#pragma unroll
    for (int r = 0; r < 4; ++r) bv[mt][r] = bias[mt * 16 + c0 + r];
#pragma unroll
    for (int kb = 0; kb < KBN; ++kb) {
      short8 f;
#pragma unroll
      for (int j = 0; j < 8; ++j) {
        int kp = kb * 32 + q8 + j;
        int k = kp / 48, i = kp - 48 * k;
        f[j] = (kp < 240)
             ? (short)f2bf(wgt[(mt * 16 + l15) * (C_ * K_) + i * K_ + k])
             : (short)0;
      }
      Aw[mt][kb] = f;
    }
  }
}

// Fused dual-batch step: two independent recurrence chains interleave in one
// wave -> MFMA pipe stays fed during the other chain's latency/VALU.
// Carry reads/writes: in-row XOR-bit4(row-bit3) swizzle (identical involution
// on both sides; conflict-free b128).
template<int NTW, int SPL>
__device__ __forceinline__ void dual_step(
    const char* __restrict__ scrA, char* __restrict__ scwA,
    const char* __restrict__ scrB, char* __restrict__ scwB,
    const short8 Aw[3][KBN], const f32x4 bv[3], const int offb[KBN],
    const float* __restrict__ inA, const float* __restrict__ inB, size_t inRS,
    float* __restrict__ outA, float* __restrict__ outB,
    int n0, int l15, int c0, const int wcol[3])
{
  float4 xa[NTW][3], xb[NTW][3];
#pragma unroll
  for (int nt = 0; nt < NTW; ++nt) {
    const float* pa = inA + (size_t)(n0 + nt * 16 + l15) * inRS + c0;
    const float* pb = inB + (size_t)(n0 + nt * 16 + l15) * inRS + c0;
#pragma unroll
    for (int mt = 0; mt < 3; ++mt) {
      xa[nt][mt] = *(const float4*)(pa + mt * 16);
      xb[nt][mt] = *(const float4*)(pb + mt * 16);
    }
  }
  __builtin_amdgcn_sched_barrier(0);   // loads issue before the MFMA region

  f32x4 acA[SPL][NTW][3], acB[SPL][NTW][3];
#pragma unroll
  for (int s = 0; s < SPL; ++s)
#pragma unroll
    for (int nt = 0; nt < NTW; ++nt)
#pragma unroll
      for (int mt = 0; mt < 3; ++mt) {
        acA[s][nt][mt] = (s == 0) ? bv[mt] : (f32x4){0.f, 0.f, 0.f, 0.f};
        acB[s][nt][mt] = (s == 0) ? bv[mt] : (f32x4){0.f, 0.f, 0.f, 0.f};
      }

  const char* bpA = scrA + (size_t)n0 * RB;
  const char* bpB = scrB + (size_t)n0 * RB;
#pragma unroll
  for (int kb = 0; kb < KBN; ++kb) {
    short8 pfa[NTW], pfb[NTW];
#pragma unroll
    for (int nt = 0; nt < NTW; ++nt) {
      pfa[nt] = *(const short8*)(bpA + nt * (16 * RB) + offb[kb]);
      pfb[nt] = *(const short8*)(bpB + nt * (16 * RB) + offb[kb]);
    }
#pragma unroll
    for (int nt = 0; nt < NTW; ++nt)
#pragma unroll
      for (int mt = 0; mt < 3; ++mt) {
        acA[kb % SPL][nt][mt] = __builtin_amdgcn_mfma_f32_16x16x32_bf16(
            Aw[mt][kb], pfa[nt], acA[kb % SPL][nt][mt], 0, 0, 0);
        acB[kb % SPL][nt][mt] = __builtin_amdgcn_mfma_f32_16x16x32_bf16(
            Aw[mt][kb], pfb[nt], acB[kb % SPL][nt][mt], 0, 0, 0);
      }
  }

#pragma unroll
  for (int nt = 0; nt < NTW; ++nt) {
    const int grow = n0 + nt * 16 + l15;
    float* oa = outA + (size_t)grow * C_ + c0;
    float* ob = outB + (size_t)grow * C_ + c0;
    char* wa = scwA + (size_t)(grow + 2) * RB;
    char* wb = scwB + (size_t)(grow + 2) * RB;
#pragma unroll
    for (int mt = 0; mt < 3; ++mt) {
      f32x4 a = acA[0][nt][mt];
#pragma unroll
      for (int s = 1; s < SPL; ++s)
#pragma unroll
        for (int r = 0; r < 4; ++r) a[r] += acA[s][nt][mt][r];
      float4 va;
      va.x = a[0] + xa[nt][mt].x; va.y = a[1] + xa[nt][mt].y;
      va.z = a[2] + xa[nt][mt].z; va.w = a[3] + xa[nt][mt].w;
      *(float4*)(oa + mt * 16) = va;
      uint2 pka; pka.x = pk2(va.x, va.y); pka.y = pk2(va.z, va.w);
      *(uint2*)(wa + wcol[mt]) = pka;

      f32x4 b2 = acB[0][nt][mt];
#pragma unroll
      for (int s = 1; s < SPL; ++s)
#pragma unroll
        for (int r = 0; r < 4; ++r) b2[r] += acB[s][nt][mt][r];
      float4 vb;
      vb.x = b2[0] + xb[nt][mt].x; vb.y = b2[1] + xb[nt][mt].y;
      vb.z = b2[2] + xb[nt][mt].z; vb.w = b2[3] + xb[nt][mt].w;
      *(float4*)(ob + mt * 16) = vb;
      uint2 pkb; pkb.x = pk2(vb.x, vb.y); pkb.y = pk2(vb.z, vb.w);
      *(uint2*)(wb + wcol[mt]) = pkb;
    }
  }
  lbar();
}

// Pass-initial: carry = inp, out = inp (both batches).
template<int NTW>
__device__ __forceinline__ void init_dual(
    char* __restrict__ scwA, char* __restrict__ scwB,
    const float* __restrict__ inA, const float* __restrict__ inB, size_t inRS,
    float* __restrict__ outA, float* __restrict__ outB,
    int n0, int l15, int c0, const int wcol[3])
{
#pragma unroll
  for (int nt = 0; nt < NTW; ++nt) {
    const int grow = n0 + nt * 16 + l15;
    const float* pa = inA + (size_t)grow * inRS + c0;
    const float* pb = inB + (size_t)grow * inRS + c0;
    float* oa = outA + (size_t)grow * C_ + c0;
    float* ob = outB + (size_t)grow * C_ + c0;
    char* wa = scwA + (size_t)(grow + 2) * RB;
    char* wb = scwB + (size_t)(grow + 2) * RB;
#pragma unroll
    for (int mt = 0; mt < 3; ++mt) {
      float4 va = *(const float4*)(pa + mt * 16);
      float4 vb = *(const float4*)(pb + mt * 16);
      *(float4*)(oa + mt * 16) = va;
      *(float4*)(ob + mt * 16) = vb;
      uint2 pka; pka.x = pk2(va.x, va.y); pka.y = pk2(va.z, va.w);
      uint2 pkb; pkb.x = pk2(vb.x, vb.y); pkb.y = pk2(vb.z, vb.w);
      *(uint2*)(wa + wcol[mt]) = pka;
      *(uint2*)(wb + wcol[mt]) = pkb;
    }
  }
  lbar();
}

// 16 blocks x 256 thr; block handles batches (2bid, 2bid+1) through all 4 passes.
__global__ __launch_bounds__(256, 1) void scnn_mfma(
    float* ws,                       // xT [b][h][w][c]; then R/L [b][t][h][c] (alias)
    const float* __restrict__ dw, const float* __restrict__ db,
    const float* __restrict__ rw, const float* __restrict__ rb,
    const float* __restrict__ lw, const float* __restrict__ lb,
    float* __restrict__ DU)          // d_out: D/U slabs [b][h][w][c]
{
  __shared__ __align__(32) ushort sball[2][2 * CBUF];   // 60928 B: [batch][dbuf]
  const int tid = threadIdx.x, lane = tid & 63, wid = tid >> 6;
  const int l15 = lane & 15, q = lane >> 4, q8 = q * 8, c0 = 4 * q;
  const int bA = blockIdx.x * 2, bB = bA + 1;

  float* xbufA = ws + (size_t)bA * SLAB;  float* xbufB = ws + (size_t)bB * SLAB;
  float* rlA   = xbufA;                   float* rlB   = xbufB;
  float* duA   = DU + (size_t)bA * SLAB;  float* duB   = DU + (size_t)bB * SLAB;
  char* sbA = (char*)&sball[0][0];
  char* sbB = (char*)&sball[1][0];
  const int n0w = wid * 32, n0h = wid * 16;

  // swizzled carry read offsets (bytes): row e = l15+k, in-row col i0*2;
  // XOR bit4 of the IN-ROW column with row-bit3 (matches write side exactly)
  int offb[KBN];
#pragma unroll
  for (int kb = 0; kb < KBN; ++kb) {
    int s = kb * 32 + q8;
    int k = s / 48, i0 = s - 48 * k;
    int e = l15 + k;
    offb[kb] = e * RB + ((i0 * 2) ^ ((((e >> 3) & 1)) << 4));
  }
  // swizzled carry write column offsets (bytes), write row e = l15+2
  const int wswz = (((l15 + 2) >> 3) & 1) << 4;
  int wcol[3];
#pragma unroll
  for (int mt = 0; mt < 3; ++mt) wcol[mt] = mt * 32 + ((q * 8) ^ wswz);

  short8 Aw[3][KBN];
  f32x4 bv[3];
  int p = 0;

  // ---------------- DOWN: d[h] = x[h] + convW(d[h-1]) ----------------
  load_wA(dw, db, Aw, bv, l15, q8, c0);
  { unsigned* z = (unsigned*)&sball[0][0];
    for (int i = tid; i < CBUF; i += 256) { z[i] = 0u; z[i + CBUF] = 0u; } }
  __syncthreads();
  init_dual<2>(sbA, sbB, xbufA, xbufB, (size_t)C_, duA, duB, n0w, l15, c0, wcol);
  for (int s = 1; s < H_; ++s) {
    dual_step<2, 1>(sbA + p * CBYTES, sbA + (p ^ 1) * CBYTES,
                    sbB + p * CBYTES, sbB + (p ^ 1) * CBYTES, Aw, bv, offb,
                    xbufA + (size_t)s * WC, xbufB + (size_t)s * WC, (size_t)C_,
                    duA + (size_t)s * WC, duB + (size_t)s * WC, n0w, l15, c0, wcol);
    p ^= 1;
  }
  __syncthreads();   // drain D stores (vmcnt) before UP reads them back

  // ---------------- UP (down weights; carry = D[63] persists) --------
  for (int s = 1; s < H_; ++s) {
    int ih = (s <= H_ - 2) ? (H_ - 2 - s) : (H_ - 1);
    dual_step<2, 1>(sbA + p * CBYTES, sbA + (p ^ 1) * CBYTES,
                    sbB + p * CBYTES, sbB + (p ^ 1) * CBYTES, Aw, bv, offb,
                    duA + (size_t)ih * WC, duB + (size_t)ih * WC, (size_t)C_,
                    duA + (size_t)(H_ - 1 - s) * WC, duB + (size_t)(H_ - 1 - s) * WC,
                    n0w, l15, c0, wcol);
    p ^= 1;
  }
  __syncthreads();   // RIGHT reads du columns written by other waves

  // ---------------- RIGHT: r[t] = U[...,t] + convH(r[t-1]) -----------
  load_wA(rw, rb, Aw, bv, l15, q8, c0);
  { unsigned* z = (unsigned*)&sball[0][0];
    for (int i = tid; i < CBUF; i += 256) { z[i] = 0u; z[i + CBUF] = 0u; } }
  __syncthreads();
  p = 0;
  init_dual<1>(sbA, sbB, duA, duB, (size_t)WC, rlA, rlB, n0h, l15, c0, wcol);
  for (int s = 1; s < W_; ++s) {
    dual_step<1, 2>(sbA + p * CBYTES, sbA + (p ^ 1) * CBYTES,
                    sbB + p * CBYTES, sbB + (p ^ 1) * CBYTES, Aw, bv, offb,
                    duA + (size_t)s * C_, duB + (size_t)s * C_, (size_t)WC,
                    rlA + (size_t)s * HC, rlB + (size_t)s * HC, n0h, l15, c0, wcol);
    p ^= 1;
  }
  __syncthreads();   // drain R stores before LEFT reads them back

  // ---------------- LEFT (carry = R[127]; L[127]=R[127] in place) ----
  load_wA(lw, lb, Aw, bv, l15, q8, c0);
  for (int s = 1; s < W_; ++s) {
    dual_step<1, 2>(sbA + p * CBYTES, sbA + (p ^ 1) * CBYTES,
                    sbB + p * CBYTES, sbB + (p ^ 1) * CBYTES, Aw, bv, offb,
                    rlA + (size_t)(W_ - 1 - s) * HC, rlB + (size_t)(W_ - 1 - s) * HC,
                    (size_t)C_,
                    rlA + (size_t)(W_ - 1 - s) * HC, rlB + (size_t)(W_ - 1 - s) * HC,
                    n0h, l15, c0, wcol);
    p ^= 1;
  }
}

// x [b][c][h][w] -> xT [b][h][w][c]
__global__ __launch_bounds__(256) void xpose_chw_hwc(const float* __restrict__ x,
                                                     float* __restrict__ xT) {
  __shared__ float t[C_ * 129];
  const int bh = blockIdx.x, b = bh >> 6, h = bh & 63;
  const float* src = x + (size_t)b * SLAB + (size_t)h * W_;
  float* dst = xT + (size_t)b * SLAB + (size_t)h * (W_ * C_);
  for (int i = threadIdx.x; i < C_ * W_; i += 256) {
    int c = i >> 7, w = i & 127;
    t[c * 129 + w] = src[(size_t)c * (H_ * W_) + w];
  }
  __syncthreads();
  for (int i = threadIdx.x; i < C_ * W_; i += 256) {
    int w = i / C_, c = i - w * C_;
    dst[i] = t[c * 129 + w];
  }
}

// L [b][w][h][c] -> out [b][c][h][w]
__global__ __launch_bounds__(256) void xpose_whc_chw(const float* __restrict__ L,
                                                     float* __restrict__ out) {
  __shared__ float t[W_ * 49];
  const int bh = blockIdx.x, b = bh >> 6, h = bh & 63;
  const float* src = L + (size_t)b * SLAB + (size_t)h * C_;
  float* dst = out + (size_t)b * SLAB + (size_t)h * W_;
  for (int i = threadIdx.x; i < W_ * C_; i += 256) {
    int w = i / C_, c = i - w * C_;
    t[w * 49 + c] = src[(size_t)w * (H_ * C_) + c];
  }
  __syncthreads();
  for (int i = threadIdx.x; i < C_ * W_; i += 256) {
    int c = i >> 7, w = i & 127;
    dst[(size_t)c * (H_ * W_) + w] = t[w * 49 + c];
  }
}

extern "C" void kernel_launch(void* const* d_in, const int* in_sizes, int n_in,
                              void* d_out, int out_size, void* d_ws, size_t ws_size,
                              hipStream_t stream) {
  const float* x  = (const float*)d_in[0];
  const float* dw = (const float*)d_in[1];
  const float* db = (const float*)d_in[2];
  const float* rw = (const float*)d_in[3];
  const float* rb = (const float*)d_in[4];
  const float* lw = (const float*)d_in[5];
  const float* lb = (const float*)d_in[6];
  float* DU = (float*)d_out;
  float* WS = (float*)d_ws;

  xpose_chw_hwc<<<B_ * H_, 256, 0, stream>>>(x, WS);
  scnn_mfma<<<B_ / 2, 256, 0, stream>>>(WS, dw, db, rw, rb, lw, lb, DU);
  xpose_whc_chw<<<B_ * H_, 256, 0, stream>>>(WS, DU);
}

// Round 10
// 887.863 us; speedup vs baseline: 1.2356x; 1.2356x over previous
//
#include <hip/hip_runtime.h>
#include <hip/hip_bf16.h>

#define B_ 32
#define C_ 48
#define H_ 64
#define W_ 128
#define K_ 5
#define SLAB (C_*H_*W_)
#define RS 56                 // carry row stride in bf16 shorts (112 B)
#define ROWS 136              // 128 rows + halo; tail rows stay zero
#define CBUF (ROWS*RS)        // 7616 shorts per buffer (15232 B)
#define WC (W_*C_)
#define HC (H_*C_)
#define KBN 8                 // dense K' = 256: k' = k*48 + i (240 real + 16 pad)

typedef __attribute__((ext_vector_type(8))) short short8;
typedef __attribute__((ext_vector_type(4))) float f32x4;
typedef unsigned short ushort;

__device__ __forceinline__ void lbar() {
  asm volatile("s_waitcnt lgkmcnt(0)\n\ts_barrier" ::: "memory");
}

__device__ __forceinline__ unsigned short f2bf(float f) {
  union { float f; unsigned u; } v; v.f = f;
  unsigned r = v.u + 0x7fffu + ((v.u >> 16) & 1u);
  return (unsigned short)(r >> 16);
}

__device__ __forceinline__ unsigned pk2(float a, float b) {
  union { __hip_bfloat162 h; unsigned u; } z;
  z.h = __float22bfloat162_rn(float2{a, b});
  return z.u;
}

// Weights as MFMA A operand, dense K' (k' = k*48 + i; pad 240..255 -> 0).
__device__ __forceinline__ void load_wA(const float* __restrict__ wgt,
                                        const float* __restrict__ bias,
                                        short8 Aw[3][KBN], f32x4 bv[3],
                                        int l15, int q8, int c0) {
#pragma unroll
  for (int mt = 0; mt < 3; ++mt) {
#pragma unroll
    for (int r = 0; r < 4; ++r) bv[mt][r] = bias[mt * 16 + c0 + r];
#pragma unroll
    for (int kb = 0; kb < KBN; ++kb) {
      short8 f;
#pragma unroll
      for (int j = 0; j < 8; ++j) {
        int kp = kb * 32 + q8 + j;
        int k = kp / 48, i = kp - 48 * k;
        f[j] = (kp < 240)
             ? (short)f2bf(wgt[(mt * 16 + l15) * (C_ * K_) + i * K_ + k])
             : (short)0;
      }
      Aw[mt][kb] = f;
    }
  }
}

// One step: out = conv(carry[scr]) + inp + bias; carry[scw] <- out.
// Inputs loaded at step top (sched_barrier keeps them above the MFMA region;
// their latency hides under the ~930cy MFMA block). One light barrier.
template<int NTW, int SPL>
__device__ __forceinline__ void do_step(const ushort* __restrict__ scr,
                                        ushort* __restrict__ scw,
                                        const short8 Aw[3][KBN], const f32x4 bv[3],
                                        const int off_r[KBN],
                                        const float* __restrict__ inp, size_t inRS,
                                        float* __restrict__ outp,
                                        int n0, int l15, int c0) {
  float4 xv[NTW][3];
#pragma unroll
  for (int nt = 0; nt < NTW; ++nt) {
    const float* p = inp + (size_t)(n0 + nt * 16 + l15) * inRS + c0;
#pragma unroll
    for (int mt = 0; mt < 3; ++mt) xv[nt][mt] = *(const float4*)(p + mt * 16);
  }
  __builtin_amdgcn_sched_barrier(0);

  f32x4 acc[SPL][NTW][3];
#pragma unroll
  for (int s = 0; s < SPL; ++s)
#pragma unroll
    for (int nt = 0; nt < NTW; ++nt)
#pragma unroll
      for (int mt = 0; mt < 3; ++mt)
        acc[s][nt][mt] = (s == 0) ? bv[mt] : (f32x4){0.f, 0.f, 0.f, 0.f};

#pragma unroll
  for (int kb = 0; kb < KBN; ++kb) {
    short8 pf[NTW];
#pragma unroll
    for (int nt = 0; nt < NTW; ++nt)
      pf[nt] = *(const short8*)(scr + (size_t)(n0 + nt * 16) * RS + off_r[kb]);
#pragma unroll
    for (int nt = 0; nt < NTW; ++nt)
#pragma unroll
      for (int mt = 0; mt < 3; ++mt)
        acc[kb % SPL][nt][mt] = __builtin_amdgcn_mfma_f32_16x16x32_bf16(
            Aw[mt][kb], pf[nt], acc[kb % SPL][nt][mt], 0, 0, 0);
  }

#pragma unroll
  for (int nt = 0; nt < NTW; ++nt) {
    const int row = n0 + nt * 16 + l15;
#pragma unroll
    for (int mt = 0; mt < 3; ++mt) {
      f32x4 a = acc[0][nt][mt];
#pragma unroll
      for (int s = 1; s < SPL; ++s)
#pragma unroll
        for (int r = 0; r < 4; ++r) a[r] += acc[s][nt][mt][r];
      float4 v;
      v.x = a[0] + xv[nt][mt].x; v.y = a[1] + xv[nt][mt].y;
      v.z = a[2] + xv[nt][mt].z; v.w = a[3] + xv[nt][mt].w;
      *(float4*)(outp + (size_t)row * C_ + mt * 16 + c0) = v;
      uint2 pk; pk.x = pk2(v.x, v.y); pk.y = pk2(v.z, v.w);
      *(uint2*)(scw + (size_t)(row + 2) * RS + mt * 16 + c0) = pk;
    }
  }
  lbar();
}

// Pass-initial: carry = inp, out = inp.
template<int NTW>
__device__ __forceinline__ void init_store(ushort* __restrict__ scw,
                                           const float* __restrict__ inp, size_t inRS,
                                           float* __restrict__ outp,
                                           int n0, int l15, int c0) {
#pragma unroll
  for (int nt = 0; nt < NTW; ++nt) {
    const int row = n0 + nt * 16 + l15;
    const float* p = inp + (size_t)row * inRS + c0;
#pragma unroll
    for (int mt = 0; mt < 3; ++mt) {
      float4 v = *(const float4*)(p + mt * 16);
      *(float4*)(outp + (size_t)row * C_ + mt * 16 + c0) = v;
      uint2 pk; pk.x = pk2(v.x, v.y); pk.y = pk2(v.z, v.w);
      *(uint2*)(scw + (size_t)(row + 2) * RS + mt * 16 + c0) = pk;
    }
  }
  lbar();
}

template<int NTW, int SPL, class FIN, class FOUT>
__device__ __forceinline__ void run_pass(ushort* sb, int& p,
                                         const short8 Aw[3][KBN], const f32x4 bv[3],
                                         const int off_r[KBN],
                                         int nsteps, FIN inadr, size_t inRS, FOUT outadr,
                                         int n0, int l15, int c0) {
  for (int s = 1; s <= nsteps; ++s) {
    do_step<NTW, SPL>(sb + (size_t)p * CBUF, sb + (size_t)(p ^ 1) * CBUF,
                      Aw, bv, off_r, inadr(s), inRS, outadr(s), n0, l15, c0);
    p ^= 1;
  }
}

// 512 threads = two independent 4-wave sub-blocks (one batch each) -> 2 waves
// per SIMD. amdgpu_waves_per_eu(2,2) lifts the VGPR cap to 256/wave so the
// ~240-reg working set (96 weight regs) does NOT spill (R4/R6 failure mode).
__global__ __attribute__((amdgpu_flat_work_group_size(512, 512),
                          amdgpu_waves_per_eu(2, 2))) void scnn_mfma(
    float* ws,                       // xT [b][h][w][c]; then R/L [b][t][h][c] (alias)
    const float* __restrict__ dw, const float* __restrict__ db,
    const float* __restrict__ rw, const float* __restrict__ rb,
    const float* __restrict__ lw, const float* __restrict__ lb,
    float* __restrict__ DU)          // d_out: D/U slabs [b][h][w][c]
{
  __shared__ __align__(32) ushort sball[2][2 * CBUF];   // 60928 B
  const int tid = threadIdx.x;
  const int sub = tid >> 8, t8 = tid & 255;
  const int lane = tid & 63, wid = (tid >> 6) & 3;
  const int l15 = lane & 15, q = lane >> 4, q8 = q * 8, c0 = 4 * q;
  const int b = blockIdx.x * 2 + sub;

  float* xbuf = ws + (size_t)b * SLAB;      // consumed by DOWN before R overwrites
  float* rl   = ws + (size_t)b * SLAB;
  float* du   = DU + (size_t)b * SLAB;
  ushort* sb  = &sball[sub][0];
  const int n0w = wid * 32, n0h = wid * 16;

  // dense-K carry read offsets (shorts): row (l15 + k), col i0
  int off_r[KBN];
#pragma unroll
  for (int kb = 0; kb < KBN; ++kb) {
    int s = kb * 32 + q8;
    int k = s / 48, i0 = s - 48 * k;
    off_r[kb] = (l15 + k) * RS + i0;
  }

  short8 Aw[3][KBN];
  f32x4 bv[3];
  int p = 0;

  // ---------------- DOWN: d[h] = x[h] + convW(d[h-1]) ----------------
  load_wA(dw, db, Aw, bv, l15, q8, c0);
  { unsigned* z = (unsigned*)sb; for (int i = t8; i < CBUF; i += 256) z[i] = 0u; }
  __syncthreads();
  init_store<2>(sb, xbuf, (size_t)C_, du, n0w, l15, c0);
  run_pass<2, 2>(sb, p, Aw, bv, off_r, H_ - 1,
                 [&](int s) { return xbuf + (size_t)s * WC; }, (size_t)C_,
                 [&](int s) { return du + (size_t)s * WC; }, n0w, l15, c0);
  __syncthreads();

  // ---------------- UP (down weights; carry = D[63] persists) --------
  run_pass<2, 2>(sb, p, Aw, bv, off_r, H_ - 1,
                 [&](int s) { int ih = (s <= H_ - 2) ? (H_ - 2 - s) : (H_ - 1);
                              return du + (size_t)ih * WC; }, (size_t)C_,
                 [&](int s) { return du + (size_t)(H_ - 1 - s) * WC; }, n0w, l15, c0);
  __syncthreads();

  // ---------------- RIGHT: r[t] = U[...,t] + convH(r[t-1]) -----------
  load_wA(rw, rb, Aw, bv, l15, q8, c0);
  { unsigned* z = (unsigned*)sb; for (int i = t8; i < CBUF; i += 256) z[i] = 0u; }
  __syncthreads();
  p = 0;
  init_store<1>(sb, du, (size_t)WC, rl, n0h, l15, c0);
  run_pass<1, 4>(sb, p, Aw, bv, off_r, W_ - 1,
                 [&](int s) { return du + (size_t)s * C_; }, (size_t)WC,
                 [&](int s) { return rl + (size_t)s * HC; }, n0h, l15, c0);
  __syncthreads();

  // ---------------- LEFT (carry = R[127]; L[127]=R[127] in place) ----
  load_wA(lw, lb, Aw, bv, l15, q8, c0);
  run_pass<1, 4>(sb, p, Aw, bv, off_r, W_ - 1,
                 [&](int s) { return rl + (size_t)(W_ - 1 - s) * HC; }, (size_t)C_,
                 [&](int s) { return rl + (size_t)(W_ - 1 - s) * HC; }, n0h, l15, c0);
}

// x [b][c][h][w] -> xT [b][h][w][c]
__global__ __launch_bounds__(256) void xpose_chw_hwc(const float* __restrict__ x,
                                                     float* __restrict__ xT) {
  __shared__ float t[C_ * 129];
  const int bh = blockIdx.x, b = bh >> 6, h = bh & 63;
  const float* src = x + (size_t)b * SLAB + (size_t)h * W_;
  float* dst = xT + (size_t)b * SLAB + (size_t)h * (W_ * C_);
  for (int i = threadIdx.x; i < C_ * W_; i += 256) {
    int c = i >> 7, w = i & 127;
    t[c * 129 + w] = src[(size_t)c * (H_ * W_) + w];
  }
  __syncthreads();
  for (int i = threadIdx.x; i < C_ * W_; i += 256) {
    int w = i / C_, c = i - w * C_;
    dst[i] = t[c * 129 + w];
  }
}

// L [b][w][h][c] -> out [b][c][h][w]
__global__ __launch_bounds__(256) void xpose_whc_chw(const float* __restrict__ L,
                                                     float* __restrict__ out) {
  __shared__ float t[W_ * 49];
  const int bh = blockIdx.x, b = bh >> 6, h = bh & 63;
  const float* src = L + (size_t)b * SLAB + (size_t)h * C_;
  float* dst = out + (size_t)b * SLAB + (size_t)h * W_;
  for (int i = threadIdx.x; i < W_ * C_; i += 256) {
    int w = i / C_, c = i - w * C_;
    t[w * 49 + c] = src[(size_t)w * (H_ * C_) + c];
  }
  __syncthreads();
  for (int i = threadIdx.x; i < C_ * W_; i += 256) {
    int c = i >> 7, w = i & 127;
    dst[(size_t)c * (H_ * W_) + w] = t[w * 49 + c];
  }
}

extern "C" void kernel_launch(void* const* d_in, const int* in_sizes, int n_in,
                              void* d_out, int out_size, void* d_ws, size_t ws_size,
                              hipStream_t stream) {
  const float* x  = (const float*)d_in[0];
  const float* dw = (const float*)d_in[1];
  const float* db = (const float*)d_in[2];
  const float* rw = (const float*)d_in[3];
  const float* rb = (const float*)d_in[4];
  const float* lw = (const float*)d_in[5];
  const float* lb = (const float*)d_in[6];
  float* DU = (float*)d_out;
  float* WS = (float*)d_ws;

  xpose_chw_hwc<<<B_ * H_, 256, 0, stream>>>(x, WS);
  scnn_mfma<<<B_ / 2, 512, 0, stream>>>(WS, dw, db, rw, rb, lw, lb, DU);
  xpose_whc_chw<<<B_ * H_, 256, 0, stream>>>(WS, DU);
}

// Round 11
// 602.570 us; speedup vs baseline: 1.8206x; 1.4735x over previous
//
#include <hip/hip_runtime.h>
#include <hip/hip_bf16.h>

#define B_ 32
#define C_ 48
#define H_ 64
#define W_ 128
#define K_ 5
#define SLAB (C_*H_*W_)
#define RS 56                 // carry row stride in bf16 shorts (112 B)
#define ROWS 136              // 128 rows + halo; tail rows stay zero
#define CBUF (ROWS*RS)        // 7616 shorts per buffer (15232 B)
#define WC (W_*C_)
#define HC (H_*C_)
#define KBN 8                 // dense K' = 256: k' = k*48 + i (240 real + 16 pad)

typedef __attribute__((ext_vector_type(8))) short short8;
typedef __attribute__((ext_vector_type(4))) float f32x4;
typedef unsigned short ushort;

__device__ __forceinline__ void lbar() {
  asm volatile("s_waitcnt lgkmcnt(0)\n\ts_barrier" ::: "memory");
}

__device__ __forceinline__ unsigned short f2bf(float f) {
  union { float f; unsigned u; } v; v.f = f;
  unsigned r = v.u + 0x7fffu + ((v.u >> 16) & 1u);
  return (unsigned short)(r >> 16);
}

__device__ __forceinline__ unsigned pk2(float a, float b) {
  union { __hip_bfloat162 h; unsigned u; } z;
  z.h = __float22bfloat162_rn(float2{a, b});
  return z.u;
}

// Weights as MFMA A operand, dense K' (k' = k*48 + i; pad 240..255 -> 0).
__device__ __forceinline__ void load_wA(const float* __restrict__ wgt,
                                        const float* __restrict__ bias,
                                        short8 Aw[3][KBN], f32x4 bv[3],
                                        int l15, int q8, int c0) {
#pragma unroll
  for (int mt = 0; mt < 3; ++mt) {
#pragma unroll
    for (int r = 0; r < 4; ++r) bv[mt][r] = bias[mt * 16 + c0 + r];
#pragma unroll
    for (int kb = 0; kb < KBN; ++kb) {
      short8 f;
#pragma unroll
      for (int j = 0; j < 8; ++j) {
        int kp = kb * 32 + q8 + j;
        int k = kp / 48, i = kp - 48 * k;
        f[j] = (kp < 240)
             ? (short)f2bf(wgt[(mt * 16 + l15) * (C_ * K_) + i * K_ + k])
             : (short)0;
      }
      Aw[mt][kb] = f;
    }
  }
}

// ---- W-pass step: 2 n-tiles, ds_reads issued 2 kb-groups ahead (3-slot
// rotation, fully unrolled -> static indices). Epilogue: ds_writes first.
__device__ __forceinline__ void stepW(const ushort* __restrict__ scr,
                                      ushort* __restrict__ scw,
                                      const short8 Aw[3][KBN], const f32x4 bv[3],
                                      const int off_r[KBN],
                                      const float* __restrict__ inp, size_t inRS,
                                      float* __restrict__ outp,
                                      int n0, int l15, int c0) {
  float4 xv[2][3];
#pragma unroll
  for (int nt = 0; nt < 2; ++nt) {
    const float* p = inp + (size_t)(n0 + nt * 16 + l15) * inRS + c0;
#pragma unroll
    for (int mt = 0; mt < 3; ++mt) xv[nt][mt] = *(const float4*)(p + mt * 16);
  }
  __builtin_amdgcn_sched_barrier(0);

  f32x4 acc[2][3];
#pragma unroll
  for (int nt = 0; nt < 2; ++nt)
#pragma unroll
    for (int mt = 0; mt < 3; ++mt) acc[nt][mt] = bv[mt];

  const ushort* r0 = scr + (size_t)n0 * RS;
  const ushort* r1 = scr + (size_t)(n0 + 16) * RS;

  short8 pf[3][2];                       // rotation slots; static after unroll
#pragma unroll
  for (int kb = 0; kb < 2; ++kb) {
    pf[kb][0] = *(const short8*)(r0 + off_r[kb]);
    pf[kb][1] = *(const short8*)(r1 + off_r[kb]);
  }
#pragma unroll
  for (int kb = 0; kb < KBN; ++kb) {
    if (kb + 2 < KBN) {
      pf[(kb + 2) % 3][0] = *(const short8*)(r0 + off_r[kb + 2]);
      pf[(kb + 2) % 3][1] = *(const short8*)(r1 + off_r[kb + 2]);
    }
#pragma unroll
    for (int nt = 0; nt < 2; ++nt)
#pragma unroll
      for (int mt = 0; mt < 3; ++mt)
        acc[nt][mt] = __builtin_amdgcn_mfma_f32_16x16x32_bf16(
            Aw[mt][kb], pf[kb % 3][nt], acc[nt][mt], 0, 0, 0);
  }

  float4 v[2][3];
#pragma unroll
  for (int nt = 0; nt < 2; ++nt)
#pragma unroll
    for (int mt = 0; mt < 3; ++mt) {
      v[nt][mt].x = acc[nt][mt][0] + xv[nt][mt].x;
      v[nt][mt].y = acc[nt][mt][1] + xv[nt][mt].y;
      v[nt][mt].z = acc[nt][mt][2] + xv[nt][mt].z;
      v[nt][mt].w = acc[nt][mt][3] + xv[nt][mt].w;
    }
  // ds_writes first (they gate the barrier), then global stores (vmcnt, free)
#pragma unroll
  for (int nt = 0; nt < 2; ++nt) {
    ushort* wp = scw + (size_t)(n0 + nt * 16 + l15 + 2) * RS + c0;
#pragma unroll
    for (int mt = 0; mt < 3; ++mt) {
      uint2 pk; pk.x = pk2(v[nt][mt].x, v[nt][mt].y);
      pk.y = pk2(v[nt][mt].z, v[nt][mt].w);
      *(uint2*)(wp + mt * 16) = pk;
    }
  }
#pragma unroll
  for (int nt = 0; nt < 2; ++nt) {
    float* op = outp + (size_t)(n0 + nt * 16 + l15) * C_ + c0;
#pragma unroll
    for (int mt = 0; mt < 3; ++mt) *(float4*)(op + mt * 16) = v[nt][mt];
  }
  lbar();
}

// ---- H-pass step: 1 n-tile, ALL 8 fragments preloaded, SPL=2 chains.
__device__ __forceinline__ void stepH(const ushort* __restrict__ scr,
                                      ushort* __restrict__ scw,
                                      const short8 Aw[3][KBN], const f32x4 bv[3],
                                      const int off_r[KBN],
                                      const float* __restrict__ inp, size_t inRS,
                                      float* __restrict__ outp,
                                      int n0, int l15, int c0) {
  float4 xv[3];
  {
    const float* p = inp + (size_t)(n0 + l15) * inRS + c0;
#pragma unroll
    for (int mt = 0; mt < 3; ++mt) xv[mt] = *(const float4*)(p + mt * 16);
  }
  __builtin_amdgcn_sched_barrier(0);

  const ushort* r0 = scr + (size_t)n0 * RS;
  short8 pf[KBN];
#pragma unroll
  for (int kb = 0; kb < KBN; ++kb) pf[kb] = *(const short8*)(r0 + off_r[kb]);

  f32x4 acc[2][3];
#pragma unroll
  for (int s = 0; s < 2; ++s)
#pragma unroll
    for (int mt = 0; mt < 3; ++mt)
      acc[s][mt] = (s == 0) ? bv[mt] : (f32x4){0.f, 0.f, 0.f, 0.f};

#pragma unroll
  for (int kb = 0; kb < KBN; ++kb)
#pragma unroll
    for (int mt = 0; mt < 3; ++mt)
      acc[kb % 2][mt] = __builtin_amdgcn_mfma_f32_16x16x32_bf16(
          Aw[mt][kb], pf[kb], acc[kb % 2][mt], 0, 0, 0);

  float4 v[3];
#pragma unroll
  for (int mt = 0; mt < 3; ++mt) {
    v[mt].x = acc[0][mt][0] + acc[1][mt][0] + xv[mt].x;
    v[mt].y = acc[0][mt][1] + acc[1][mt][1] + xv[mt].y;
    v[mt].z = acc[0][mt][2] + acc[1][mt][2] + xv[mt].z;
    v[mt].w = acc[0][mt][3] + acc[1][mt][3] + xv[mt].w;
  }
  ushort* wp = scw + (size_t)(n0 + l15 + 2) * RS + c0;
#pragma unroll
  for (int mt = 0; mt < 3; ++mt) {
    uint2 pk; pk.x = pk2(v[mt].x, v[mt].y); pk.y = pk2(v[mt].z, v[mt].w);
    *(uint2*)(wp + mt * 16) = pk;
  }
  float* op = outp + (size_t)(n0 + l15) * C_ + c0;
#pragma unroll
  for (int mt = 0; mt < 3; ++mt) *(float4*)(op + mt * 16) = v[mt];
  lbar();
}

// Pass-initial: carry = inp, out = inp.
template<int NTW>
__device__ __forceinline__ void init_store(ushort* __restrict__ scw,
                                           const float* __restrict__ inp, size_t inRS,
                                           float* __restrict__ outp,
                                           int n0, int l15, int c0) {
#pragma unroll
  for (int nt = 0; nt < NTW; ++nt) {
    const int row = n0 + nt * 16 + l15;
    const float* p = inp + (size_t)row * inRS + c0;
#pragma unroll
    for (int mt = 0; mt < 3; ++mt) {
      float4 v = *(const float4*)(p + mt * 16);
      *(float4*)(outp + (size_t)row * C_ + mt * 16 + c0) = v;
      uint2 pk; pk.x = pk2(v.x, v.y); pk.y = pk2(v.z, v.w);
      *(uint2*)(scw + (size_t)(row + 2) * RS + mt * 16 + c0) = pk;
    }
  }
  lbar();
}

// 4 waves (256 thr) per batch, grid 32. W passes: wave = 2 n-tiles; H: 1.
__global__ __launch_bounds__(256, 1) void scnn_mfma(
    float* ws,                       // xT [b][h][w][c]; then R/L [b][t][h][c] (alias)
    const float* __restrict__ dw, const float* __restrict__ db,
    const float* __restrict__ rw, const float* __restrict__ rb,
    const float* __restrict__ lw, const float* __restrict__ lb,
    float* __restrict__ DU)          // d_out: D/U slabs [b][h][w][c]
{
  __shared__ __align__(32) ushort sb[2 * CBUF];   // 30464 B
  const int tid = threadIdx.x, lane = tid & 63, wid = tid >> 6;
  const int l15 = lane & 15, q = lane >> 4, q8 = q * 8, c0 = 4 * q;
  const int b = blockIdx.x;
  float* xbuf = ws + (size_t)b * SLAB;      // consumed by DOWN before R overwrites
  float* rl   = ws + (size_t)b * SLAB;
  float* du   = DU + (size_t)b * SLAB;
  const int n0w = wid * 32, n0h = wid * 16;

  // dense-K carry read offsets (shorts): row (l15 + k), col i0
  int off_r[KBN];
#pragma unroll
  for (int kb = 0; kb < KBN; ++kb) {
    int s = kb * 32 + q8;
    int k = s / 48, i0 = s - 48 * k;
    off_r[kb] = (l15 + k) * RS + i0;
  }

  short8 Aw[3][KBN];
  f32x4 bv[3];
  int p = 0;

  // ---------------- DOWN: d[h] = x[h] + convW(d[h-1]) ----------------
  load_wA(dw, db, Aw, bv, l15, q8, c0);
  { unsigned* z = (unsigned*)sb; for (int i = tid; i < CBUF; i += 256) z[i] = 0u; }
  __syncthreads();
  init_store<2>(sb, xbuf, (size_t)C_, du, n0w, l15, c0);
  for (int s = 1; s < H_; ++s) {
    stepW(sb + (size_t)p * CBUF, sb + (size_t)(p ^ 1) * CBUF, Aw, bv, off_r,
          xbuf + (size_t)s * WC, (size_t)C_, du + (size_t)s * WC, n0w, l15, c0);
    p ^= 1;
  }
  __syncthreads();

  // ---------------- UP (down weights; carry = D[63] persists) --------
  for (int s = 1; s < H_; ++s) {
    int ih = (s <= H_ - 2) ? (H_ - 2 - s) : (H_ - 1);
    stepW(sb + (size_t)p * CBUF, sb + (size_t)(p ^ 1) * CBUF, Aw, bv, off_r,
          du + (size_t)ih * WC, (size_t)C_, du + (size_t)(H_ - 1 - s) * WC,
          n0w, l15, c0);
    p ^= 1;
  }
  __syncthreads();

  // ---------------- RIGHT: r[t] = U[...,t] + convH(r[t-1]) -----------
  load_wA(rw, rb, Aw, bv, l15, q8, c0);
  { unsigned* z = (unsigned*)sb; for (int i = tid; i < CBUF; i += 256) z[i] = 0u; }
  __syncthreads();
  p = 0;
  init_store<1>(sb, du, (size_t)WC, rl, n0h, l15, c0);
  for (int s = 1; s < W_; ++s) {
    stepH(sb + (size_t)p * CBUF, sb + (size_t)(p ^ 1) * CBUF, Aw, bv, off_r,
          du + (size_t)s * C_, (size_t)WC, rl + (size_t)s * HC, n0h, l15, c0);
    p ^= 1;
  }
  __syncthreads();

  // ---------------- LEFT (carry = R[127]; L[127]=R[127] in place) ----
  load_wA(lw, lb, Aw, bv, l15, q8, c0);
  for (int s = 1; s < W_; ++s) {
    stepH(sb + (size_t)p * CBUF, sb + (size_t)(p ^ 1) * CBUF, Aw, bv, off_r,
          rl + (size_t)(W_ - 1 - s) * HC, (size_t)C_,
          rl + (size_t)(W_ - 1 - s) * HC, n0h, l15, c0);
    p ^= 1;
  }
}

// x [b][c][h][w] -> xT [b][h][w][c]
__global__ __launch_bounds__(256) void xpose_chw_hwc(const float* __restrict__ x,
                                                     float* __restrict__ xT) {
  __shared__ float t[C_ * 129];
  const int bh = blockIdx.x, b = bh >> 6, h = bh & 63;
  const float* src = x + (size_t)b * SLAB + (size_t)h * W_;
  float* dst = xT + (size_t)b * SLAB + (size_t)h * (W_ * C_);
  for (int i = threadIdx.x; i < C_ * W_; i += 256) {
    int c = i >> 7, w = i & 127;
    t[c * 129 + w] = src[(size_t)c * (H_ * W_) + w];
  }
  __syncthreads();
  for (int i = threadIdx.x; i < C_ * W_; i += 256) {
    int w = i / C_, c = i - w * C_;
    dst[i] = t[c * 129 + w];
  }
}

// L [b][w][h][c] -> out [b][c][h][w]
__global__ __launch_bounds__(256) void xpose_whc_chw(const float* __restrict__ L,
                                                     float* __restrict__ out) {
  __shared__ float t[W_ * 49];
  const int bh = blockIdx.x, b = bh >> 6, h = bh & 63;
  const float* src = L + (size_t)b * SLAB + (size_t)h * C_;
  float* dst = out + (size_t)b * SLAB + (size_t)h * W_;
  for (int i = threadIdx.x; i < W_ * C_; i += 256) {
    int w = i / C_, c = i - w * C_;
    t[w * 49 + c] = src[(size_t)w * (H_ * C_) + c];
  }
  __syncthreads();
  for (int i = threadIdx.x; i < C_ * W_; i += 256) {
    int c = i >> 7, w = i & 127;
    dst[(size_t)c * (H_ * W_) + w] = t[w * 49 + c];
  }
}

extern "C" void kernel_launch(void* const* d_in, const int* in_sizes, int n_in,
                              void* d_out, int out_size, void* d_ws, size_t ws_size,
                              hipStream_t stream) {
  const float* x  = (const float*)d_in[0];
  const float* dw = (const float*)d_in[1];
  const float* db = (const float*)d_in[2];
  const float* rw = (const float*)d_in[3];
  const float* rb = (const float*)d_in[4];
  const float* lw = (const float*)d_in[5];
  const float* lb = (const float*)d_in[6];
  float* DU = (float*)d_out;
  float* WS = (float*)d_ws;

  xpose_chw_hwc<<<B_ * H_, 256, 0, stream>>>(x, WS);
  scnn_mfma<<<B_, 256, 0, stream>>>(WS, dw, db, rw, rb, lw, lb, DU);
  xpose_whc_chw<<<B_ * H_, 256, 0, stream>>>(WS, DU);
}

// Round 12
// 412.395 us; speedup vs baseline: 2.6602x; 1.4611x over previous
//
#include <hip/hip_runtime.h>
#include <hip/hip_bf16.h>

#define B_ 32
#define C_ 48
#define H_ 64
#define W_ 128
#define K_ 5
#define SLAB (C_*H_*W_)
#define RS 56                 // carry row stride in bf16 shorts (112 B)
#define ROWS 136              // 128 rows + halo; tail rows stay zero
#define CBUF (ROWS*RS)        // 7616 shorts per buffer (15232 B)
#define WC (W_*C_)
#define HC (H_*C_)
#define KBN 8                 // dense K' = 256: k' = k*48 + i (240 real + 16 pad)

typedef __attribute__((ext_vector_type(8))) short short8;
typedef __attribute__((ext_vector_type(4))) float f32x4;
typedef unsigned short ushort;

__device__ __forceinline__ void lbar() {
  asm volatile("s_waitcnt lgkmcnt(0)\n\ts_barrier" ::: "memory");
}

__device__ __forceinline__ unsigned short f2bf(float f) {
  union { float f; unsigned u; } v; v.f = f;
  unsigned r = v.u + 0x7fffu + ((v.u >> 16) & 1u);
  return (unsigned short)(r >> 16);
}

__device__ __forceinline__ unsigned pk2(float a, float b) {
  union { __hip_bfloat162 h; unsigned u; } z;
  z.h = __float22bfloat162_rn(float2{a, b});
  return z.u;
}

// Weights as MFMA A operand, dense K' (k' = k*48 + i; pad 240..255 -> 0).
__device__ __forceinline__ void load_wA(const float* __restrict__ wgt,
                                        const float* __restrict__ bias,
                                        short8 Aw[3][KBN], f32x4 bv[3],
                                        int l15, int q8, int c0) {
#pragma unroll
  for (int mt = 0; mt < 3; ++mt) {
#pragma unroll
    for (int r = 0; r < 4; ++r) bv[mt][r] = bias[mt * 16 + c0 + r];
#pragma unroll
    for (int kb = 0; kb < KBN; ++kb) {
      short8 f;
#pragma unroll
      for (int j = 0; j < 8; ++j) {
        int kp = kb * 32 + q8 + j;
        int k = kp / 48, i = kp - 48 * k;
        f[j] = (kp < 240)
             ? (short)f2bf(wgt[(mt * 16 + l15) * (C_ * K_) + i * K_ + k])
             : (short)0;
      }
      Aw[mt][kb] = f;
    }
  }
}

template<int NTW>
__device__ __forceinline__ void load_xin(float4 xv[NTW][3], const float* __restrict__ inp,
                                         size_t lRS, int n0, int l15, int c0) {
#pragma unroll
  for (int nt = 0; nt < NTW; ++nt) {
    const float* p = inp + (size_t)(n0 + nt * 16 + l15) * lRS + c0;
#pragma unroll
    for (int mt = 0; mt < 3; ++mt)
      xv[nt][mt] = *(const float4*)(p + mt * 16);
  }
}

// ---- W step: per-nt fragment PRELOAD (all 8 kb up front) so ds_read latency
// is paid once per nt, pipelined, instead of once per kb-group. nt1's reads
// hoist into nt0's MFMA shadow (compiler-scheduled, register-feasible).
__device__ __forceinline__ void do_stepW(const ushort* __restrict__ scr,
                                         ushort* __restrict__ scw,
                                         const short8 Aw[3][KBN], const f32x4 bv[3],
                                         const float4 xv[2][3], const int off_r[KBN],
                                         float* __restrict__ outp,
                                         int n0, int l15, int c0) {
  f32x4 acc[2][2][3];   // [spl][nt][mt]
#pragma unroll
  for (int nt = 0; nt < 2; ++nt)
#pragma unroll
    for (int mt = 0; mt < 3; ++mt) {
      acc[0][nt][mt] = bv[mt];
      acc[1][nt][mt] = (f32x4){0.f, 0.f, 0.f, 0.f};
    }

  const ushort* b0 = scr + (size_t)n0 * RS;
  const ushort* b1 = scr + (size_t)(n0 + 16) * RS;

  short8 p0[KBN];
#pragma unroll
  for (int kb = 0; kb < KBN; ++kb) p0[kb] = *(const short8*)(b0 + off_r[kb]);
#pragma unroll
  for (int kb = 0; kb < KBN; ++kb)
#pragma unroll
    for (int mt = 0; mt < 3; ++mt)
      acc[kb & 1][0][mt] = __builtin_amdgcn_mfma_f32_16x16x32_bf16(
          Aw[mt][kb], p0[kb], acc[kb & 1][0][mt], 0, 0, 0);

  short8 p1[KBN];
#pragma unroll
  for (int kb = 0; kb < KBN; ++kb) p1[kb] = *(const short8*)(b1 + off_r[kb]);
#pragma unroll
  for (int kb = 0; kb < KBN; ++kb)
#pragma unroll
    for (int mt = 0; mt < 3; ++mt)
      acc[kb & 1][1][mt] = __builtin_amdgcn_mfma_f32_16x16x32_bf16(
          Aw[mt][kb], p1[kb], acc[kb & 1][1][mt], 0, 0, 0);

#pragma unroll
  for (int nt = 0; nt < 2; ++nt) {
    const int row = n0 + nt * 16 + l15;
#pragma unroll
    for (int mt = 0; mt < 3; ++mt) {
      float4 v;
      v.x = acc[0][nt][mt][0] + acc[1][nt][mt][0] + xv[nt][mt].x;
      v.y = acc[0][nt][mt][1] + acc[1][nt][mt][1] + xv[nt][mt].y;
      v.z = acc[0][nt][mt][2] + acc[1][nt][mt][2] + xv[nt][mt].z;
      v.w = acc[0][nt][mt][3] + acc[1][nt][mt][3] + xv[nt][mt].w;
      *(float4*)(outp + (size_t)row * C_ + mt * 16 + c0) = v;
      uint2 pk; pk.x = pk2(v.x, v.y); pk.y = pk2(v.z, v.w);
      *(uint2*)(scw + (size_t)(row + 2) * RS + mt * 16 + c0) = pk;
    }
  }
  lbar();
}

// ---- H step: ALL 8 fragments preloaded, SPL=4 accumulator chains.
__device__ __forceinline__ void do_stepH(const ushort* __restrict__ scr,
                                         ushort* __restrict__ scw,
                                         const short8 Aw[3][KBN], const f32x4 bv[3],
                                         const float4 xv[1][3], const int off_r[KBN],
                                         float* __restrict__ outp,
                                         int n0, int l15, int c0) {
  const ushort* b0 = scr + (size_t)n0 * RS;
  short8 p[KBN];
#pragma unroll
  for (int kb = 0; kb < KBN; ++kb) p[kb] = *(const short8*)(b0 + off_r[kb]);

  f32x4 acc[4][3];
#pragma unroll
  for (int s = 0; s < 4; ++s)
#pragma unroll
    for (int mt = 0; mt < 3; ++mt)
      acc[s][mt] = (s == 0) ? bv[mt] : (f32x4){0.f, 0.f, 0.f, 0.f};

#pragma unroll
  for (int kb = 0; kb < KBN; ++kb)
#pragma unroll
    for (int mt = 0; mt < 3; ++mt)
      acc[kb & 3][mt] = __builtin_amdgcn_mfma_f32_16x16x32_bf16(
          Aw[mt][kb], p[kb], acc[kb & 3][mt], 0, 0, 0);

  const int row = n0 + l15;
#pragma unroll
  for (int mt = 0; mt < 3; ++mt) {
    float4 v;
    v.x = acc[0][mt][0] + acc[1][mt][0] + acc[2][mt][0] + acc[3][mt][0] + xv[0][mt].x;
    v.y = acc[0][mt][1] + acc[1][mt][1] + acc[2][mt][1] + acc[3][mt][1] + xv[0][mt].y;
    v.z = acc[0][mt][2] + acc[1][mt][2] + acc[2][mt][2] + acc[3][mt][2] + xv[0][mt].z;
    v.w = acc[0][mt][3] + acc[1][mt][3] + acc[2][mt][3] + acc[3][mt][3] + xv[0][mt].w;
    *(float4*)(outp + (size_t)row * C_ + mt * 16 + c0) = v;
    uint2 pk; pk.x = pk2(v.x, v.y); pk.y = pk2(v.z, v.w);
    *(uint2*)(scw + (size_t)(row + 2) * RS + mt * 16 + c0) = pk;
  }
  lbar();
}

// Pass-initial: carry = inp, out = inp.
template<int NTW>
__device__ __forceinline__ void init_store(ushort* __restrict__ scw,
                                           const float* __restrict__ inp, size_t lRS,
                                           float* __restrict__ outp,
                                           int n0, int l15, int c0) {
#pragma unroll
  for (int nt = 0; nt < NTW; ++nt) {
    const int row = n0 + nt * 16 + l15;
    const float* p = inp + (size_t)row * lRS + c0;
#pragma unroll
    for (int mt = 0; mt < 3; ++mt) {
      float4 v = *(const float4*)(p + mt * 16);
      *(float4*)(outp + (size_t)row * C_ + mt * 16 + c0) = v;
      uint2 pk; pk.x = pk2(v.x, v.y); pk.y = pk2(v.z, v.w);
      *(uint2*)(scw + (size_t)(row + 2) * RS + mt * 16 + c0) = pk;
    }
  }
  lbar();
}

// Software-pipelined W pass: prefetch xin one step ahead; double-buffered carry.
template<class FIN, class FOUT>
__device__ __forceinline__ void run_passW(ushort* sb, int& p,
                                          const short8 Aw[3][KBN], const f32x4 bv[3],
                                          const int off_r[KBN],
                                          int nsteps, FIN inadr, size_t lRS, FOUT outadr,
                                          int n0, int l15, int c0) {
  float4 xa[2][3], xb[2][3];
  load_xin<2>(xa, inadr(1), lRS, n0, l15, c0);
  for (int s = 1; s <= nsteps; s += 2) {
    {
      int sn = (s + 1 <= nsteps) ? s + 1 : nsteps;
      load_xin<2>(xb, inadr(sn), lRS, n0, l15, c0);
      __builtin_amdgcn_sched_barrier(0x38F);
      do_stepW(sb + (size_t)p * CBUF, sb + (size_t)(p ^ 1) * CBUF,
               Aw, bv, xa, off_r, outadr(s), n0, l15, c0);
      p ^= 1;
    }
    if (s + 1 <= nsteps) {
      int sn = (s + 2 <= nsteps) ? s + 2 : nsteps;
      load_xin<2>(xa, inadr(sn), lRS, n0, l15, c0);
      __builtin_amdgcn_sched_barrier(0x38F);
      do_stepW(sb + (size_t)p * CBUF, sb + (size_t)(p ^ 1) * CBUF,
               Aw, bv, xb, off_r, outadr(s + 1), n0, l15, c0);
      p ^= 1;
    }
  }
}

template<class FIN, class FOUT>
__device__ __forceinline__ void run_passH(ushort* sb, int& p,
                                          const short8 Aw[3][KBN], const f32x4 bv[3],
                                          const int off_r[KBN],
                                          int nsteps, FIN inadr, size_t lRS, FOUT outadr,
                                          int n0, int l15, int c0) {
  float4 xa[1][3], xb[1][3];
  load_xin<1>(xa, inadr(1), lRS, n0, l15, c0);
  for (int s = 1; s <= nsteps; s += 2) {
    {
      int sn = (s + 1 <= nsteps) ? s + 1 : nsteps;
      load_xin<1>(xb, inadr(sn), lRS, n0, l15, c0);
      __builtin_amdgcn_sched_barrier(0x38F);
      do_stepH(sb + (size_t)p * CBUF, sb + (size_t)(p ^ 1) * CBUF,
               Aw, bv, xa, off_r, outadr(s), n0, l15, c0);
      p ^= 1;
    }
    if (s + 1 <= nsteps) {
      int sn = (s + 2 <= nsteps) ? s + 2 : nsteps;
      load_xin<1>(xa, inadr(sn), lRS, n0, l15, c0);
      __builtin_amdgcn_sched_barrier(0x38F);
      do_stepH(sb + (size_t)p * CBUF, sb + (size_t)(p ^ 1) * CBUF,
               Aw, bv, xb, off_r, outadr(s + 1), n0, l15, c0);
      p ^= 1;
    }
  }
}

// 4 waves (256 thr) per batch, grid 32. W passes: wave = 2 n-tiles; H: 1.
__global__ __launch_bounds__(256, 1) void scnn_mfma(
    float* ws,                       // xT [b][h][w][c]; then R/L [b][t][h][c] (alias)
    const float* __restrict__ dw, const float* __restrict__ db,
    const float* __restrict__ rw, const float* __restrict__ rb,
    const float* __restrict__ lw, const float* __restrict__ lb,
    float* __restrict__ DU)          // d_out: D/U slabs [b][h][w][c]
{
  __shared__ __align__(32) ushort sb[2 * CBUF];   // 30464 B
  const int tid = threadIdx.x, lane = tid & 63, wid = tid >> 6;
  const int l15 = lane & 15, q = lane >> 4, q8 = q * 8, c0 = 4 * q;
  const int b = blockIdx.x;
  float* xbuf = ws + (size_t)b * SLAB;      // consumed by DOWN before R overwrites
  float* rl   = ws + (size_t)b * SLAB;
  float* du   = DU + (size_t)b * SLAB;
  const int n0w = wid * 32, n0h = wid * 16;

  // dense-K carry read offsets (shorts): row (l15 + k), col i0
  int off_r[KBN];
#pragma unroll
  for (int kb = 0; kb < KBN; ++kb) {
    int s = kb * 32 + q8;
    int k = s / 48, i0 = s - 48 * k;
    off_r[kb] = (l15 + k) * RS + i0;
  }

  short8 Aw[3][KBN];
  f32x4 bv[3];
  int p = 0;

  // ---------------- DOWN: d[h] = x[h] + convW(d[h-1]) ----------------
  load_wA(dw, db, Aw, bv, l15, q8, c0);
  { unsigned* z = (unsigned*)sb; for (int i = tid; i < CBUF; i += 256) z[i] = 0u; }
  __syncthreads();
  init_store<2>(sb, xbuf, (size_t)C_, du, n0w, l15, c0);
  run_passW(sb, p, Aw, bv, off_r, H_ - 1,
            [&](int s) { return xbuf + (size_t)s * WC; }, (size_t)C_,
            [&](int s) { return du + (size_t)s * WC; }, n0w, l15, c0);
  __syncthreads();

  // ---------------- UP (down weights; carry = D[63] persists) --------
  run_passW(sb, p, Aw, bv, off_r, H_ - 1,
            [&](int s) { int ih = (s <= H_ - 2) ? (H_ - 2 - s) : (H_ - 1);
                         return du + (size_t)ih * WC; }, (size_t)C_,
            [&](int s) { return du + (size_t)(H_ - 1 - s) * WC; }, n0w, l15, c0);
  __syncthreads();

  // ---------------- RIGHT: r[t] = U[...,t] + convH(r[t-1]) -----------
  load_wA(rw, rb, Aw, bv, l15, q8, c0);
  { unsigned* z = (unsigned*)sb; for (int i = tid; i < CBUF; i += 256) z[i] = 0u; }
  __syncthreads();
  p = 0;
  init_store<1>(sb, du, (size_t)WC, rl, n0h, l15, c0);
  run_passH(sb, p, Aw, bv, off_r, W_ - 1,
            [&](int s) { return du + (size_t)s * C_; }, (size_t)WC,
            [&](int s) { return rl + (size_t)s * HC; }, n0h, l15, c0);
  __syncthreads();

  // ---------------- LEFT (carry = R[127]; L[127]=R[127] in place) ----
  load_wA(lw, lb, Aw, bv, l15, q8, c0);
  run_passH(sb, p, Aw, bv, off_r, W_ - 1,
            [&](int s) { return rl + (size_t)(W_ - 1 - s) * HC; }, (size_t)C_,
            [&](int s) { return rl + (size_t)(W_ - 1 - s) * HC; }, n0h, l15, c0);
}

// x [b][c][h][w] -> xT [b][h][w][c]
__global__ __launch_bounds__(256) void xpose_chw_hwc(const float* __restrict__ x,
                                                     float* __restrict__ xT) {
  __shared__ float t[C_ * 129];
  const int bh = blockIdx.x, b = bh >> 6, h = bh & 63;
  const float* src = x + (size_t)b * SLAB + (size_t)h * W_;
  float* dst = xT + (size_t)b * SLAB + (size_t)h * (W_ * C_);
  for (int i = threadIdx.x; i < C_ * W_; i += 256) {
    int c = i >> 7, w = i & 127;
    t[c * 129 + w] = src[(size_t)c * (H_ * W_) + w];
  }
  __syncthreads();
  for (int i = threadIdx.x; i < C_ * W_; i += 256) {
    int w = i / C_, c = i - w * C_;
    dst[i] = t[c * 129 + w];
  }
}

// L [b][w][h][c] -> out [b][c][h][w]
__global__ __launch_bounds__(256) void xpose_whc_chw(const float* __restrict__ L,
                                                     float* __restrict__ out) {
  __shared__ float t[W_ * 49];
  const int bh = blockIdx.x, b = bh >> 6, h = bh & 63;
  const float* src = L + (size_t)b * SLAB + (size_t)h * C_;
  float* dst = out + (size_t)b * SLAB + (size_t)h * W_;
  for (int i = threadIdx.x; i < W_ * C_; i += 256) {
    int w = i / C_, c = i - w * C_;
    t[w * 49 + c] = src[(size_t)w * (H_ * C_) + c];
  }
  __syncthreads();
  for (int i = threadIdx.x; i < C_ * W_; i += 256) {
    int c = i >> 7, w = i & 127;
    dst[(size_t)c * (H_ * W_) + w] = t[w * 49 + c];
  }
}

extern "C" void kernel_launch(void* const* d_in, const int* in_sizes, int n_in,
                              void* d_out, int out_size, void* d_ws, size_t ws_size,
                              hipStream_t stream) {
  const float* x  = (const float*)d_in[0];
  const float* dw = (const float*)d_in[1];
  const float* db = (const float*)d_in[2];
  const float* rw = (const float*)d_in[3];
  const float* rb = (const float*)d_in[4];
  const float* lw = (const float*)d_in[5];
  const float* lb = (const float*)d_in[6];
  float* DU = (float*)d_out;
  float* WS = (float*)d_ws;

  xpose_chw_hwc<<<B_ * H_, 256, 0, stream>>>(x, WS);
  scnn_mfma<<<B_, 256, 0, stream>>>(WS, dw, db, rw, rb, lw, lb, DU);
  xpose_whc_chw<<<B_ * H_, 256, 0, stream>>>(WS, DU);
}